// Round 1
// baseline (309.667 us; speedup 1.0000x reference)
//
#include <hip/hip_runtime.h>
#include <cstdint>
#include <cstddef>

#define B_   32
#define N_   256
#define C_   256
#define DFF_ 1024

// ---------------- grid indices: per-batch min + cell index ----------------
__global__ void k_grid_idx(const float* __restrict__ coords,
                           int* __restrict__ ge, int* __restrict__ gp) {
    int b = blockIdx.x, n = threadIdx.x;
    float eta = coords[(b * N_ + n) * 2 + 0];
    float phi = coords[(b * N_ + n) * 2 + 1];
    __shared__ float se[N_], sp[N_];
    se[n] = eta; sp[n] = phi;
    __syncthreads();
    for (int s = 128; s > 0; s >>= 1) {
        if (n < s) {
            se[n] = fminf(se[n], se[n + s]);
            sp[n] = fminf(sp[n], sp[n + s]);
        }
        __syncthreads();
    }
    float emin = se[0], pmin = sp[0];
    int gi = (int)((eta - emin) / 0.1f); gi = gi < 0 ? 0 : (gi > 127 ? 127 : gi);
    int pi = (int)((phi - pmin) / 0.1f); pi = pi < 0 ? 0 : (pi > 127 ? 127 : pi);
    ge[b * N_ + n] = gi;
    gp[b * N_ + n] = pi;
}

// ------------- CPE: scatter->dwconv->gather collapsed to pair-sum ----------
// out[b,n,c] = sum_m dwk[(ge_m-ge_n+3)*8 + (gp_m-gp_n+3)][c] * x[b,m,c] + dwb[c]
__global__ void k_cpe(const float* __restrict__ x,
                      const int* __restrict__ ge, const int* __restrict__ gp,
                      const float* __restrict__ dwk, const float* __restrict__ dwb,
                      float* __restrict__ t0) {
    int bn = blockIdx.x;
    int b = bn >> 8, n = bn & 255;
    int c = threadIdx.x;
    __shared__ int sge[N_], sgp[N_];
    sge[c] = ge[b * N_ + c];
    sgp[c] = gp[b * N_ + c];
    __syncthreads();
    int gn = sge[n], pn = sgp[n];
    const float* xb = x + (size_t)b * N_ * C_;
    float acc = 0.f;
    for (int m = 0; m < N_; ++m) {
        int dh = sge[m] - gn + 3;
        int dv = sgp[m] - pn + 3;
        if (((unsigned)dh < 8u) && ((unsigned)dv < 8u)) {
            acc = fmaf(dwk[(dh * 8 + dv) * C_ + c], xb[m * C_ + c], acc);
        }
    }
    t0[(size_t)bn * C_ + c] = acc + dwb[c];
}

// ---------------- BN inference scale/shift precompute ----------------
__global__ void k_bnprep(const float* g0, const float* b0, const float* m0, const float* v0,
                         const float* g1, const float* b1, const float* m1, const float* v1,
                         const float* g2, const float* b2, const float* m2, const float* v2,
                         float* __restrict__ sh) {
    int c = threadIdx.x;
    float s;
    s = g0[c] * rsqrtf(v0[c] + 1e-3f); sh[c]        = s; sh[256 + c]  = b0[c] - m0[c] * s;
    s = g1[c] * rsqrtf(v1[c] + 1e-3f); sh[512 + c]  = s; sh[768 + c]  = b1[c] - m1[c] * s;
    s = g2[c] * rsqrtf(v2[c] + 1e-3f); sh[1024 + c] = s; sh[1280 + c] = b2[c] - m2[c] * s;
}

// ---------------- generic tiled fp32 GEMM with fused epilogues ----------------
// EPI 0: C = A@W + bias
// EPI 1: C = relu(A@W + bias)
// EPI 2: t = A@W + bias + gvec[b,col]; y = t*s0+h0; C = (resid + y)*s1 + h1
// EPI 3: o = A@W + bias; C = (resid + o)*s0 + h0
template <int EPI>
__global__ __launch_bounds__(256) void k_gemm(
    const float* __restrict__ A, const float* __restrict__ W,
    const float* __restrict__ bias, float* __restrict__ Cc,
    int M, int Nn, int K,
    const float* __restrict__ resid, const float* __restrict__ gvec,
    const float* __restrict__ s0, const float* __restrict__ h0,
    const float* __restrict__ s1, const float* __restrict__ h1) {
    __shared__ float sAT[32][68];   // A tile transposed, padded (272B rows, 16B-aligned)
    __shared__ float sB[32][64];
    int tid = threadIdx.x;
    int tx = tid & 15, ty = tid >> 4;
    int rowBase = blockIdx.y * 64, colBase = blockIdx.x * 64;
    float acc[4][4] = {};

    for (int k0 = 0; k0 < K; k0 += 32) {
        // stage A tile (64x32) transposed into LDS
        #pragma unroll
        for (int l = 0; l < 2; ++l) {
            int q = tid + l * 256;
            int r = q >> 3, k4 = (q & 7) << 2;
            float4 a = *(const float4*)(A + (size_t)(rowBase + r) * K + k0 + k4);
            sAT[k4 + 0][r] = a.x; sAT[k4 + 1][r] = a.y;
            sAT[k4 + 2][r] = a.z; sAT[k4 + 3][r] = a.w;
        }
        // stage B tile (32x64)
        #pragma unroll
        for (int l = 0; l < 2; ++l) {
            int q = tid + l * 256;
            int kk = q >> 4, j4 = (q & 15) << 2;
            *(float4*)(&sB[kk][j4]) = *(const float4*)(W + (size_t)(k0 + kk) * Nn + colBase + j4);
        }
        __syncthreads();
        #pragma unroll
        for (int k = 0; k < 32; ++k) {
            float4 av = *(const float4*)(&sAT[k][ty << 2]);
            float4 bv = *(const float4*)(&sB[k][tx << 2]);
            float aa[4] = {av.x, av.y, av.z, av.w};
            float bb[4] = {bv.x, bv.y, bv.z, bv.w};
            #pragma unroll
            for (int i = 0; i < 4; ++i)
                #pragma unroll
                for (int j = 0; j < 4; ++j)
                    acc[i][j] = fmaf(aa[i], bb[j], acc[i][j]);
        }
        __syncthreads();
    }

    #pragma unroll
    for (int i = 0; i < 4; ++i) {
        int row = rowBase + (ty << 2) + i;
        int col0 = colBase + (tx << 2);
        float out[4];
        #pragma unroll
        for (int j = 0; j < 4; ++j) {
            int col = col0 + j;
            float v = acc[i][j] + bias[col];
            if constexpr (EPI == 1) {
                v = v > 0.f ? v : 0.f;
            } else if constexpr (EPI == 2) {
                v += gvec[(row >> 8) * C_ + col];
                v = v * s0[col] + h0[col];
                float xv = resid[(size_t)row * C_ + col];
                v = (xv + v) * s1[col] + h1[col];
            } else if constexpr (EPI == 3) {
                float xv = resid[(size_t)row * C_ + col];
                v = (xv + v) * s0[col] + h0[col];
            }
            out[j] = v;
        }
        *(float4*)(Cc + (size_t)row * Nn + col0) = make_float4(out[0], out[1], out[2], out[3]);
    }
}

// ---------------- LayerNorm(h) + residual x ----------------
__global__ void k_ln_resid(const float* __restrict__ h, const float* __restrict__ x,
                           const float* __restrict__ g, const float* __restrict__ bta,
                           float* __restrict__ x1) {
    int row = blockIdx.x, c = threadIdx.x;
    float v = h[(size_t)row * C_ + c];
    __shared__ float red[C_];
    red[c] = v;
    __syncthreads();
    for (int s = 128; s > 0; s >>= 1) {
        if (c < s) red[c] += red[c + s];
        __syncthreads();
    }
    float mu = red[0] * (1.f / C_);
    __syncthreads();
    float d = v - mu;
    red[c] = d * d;
    __syncthreads();
    for (int s = 128; s > 0; s >>= 1) {
        if (c < s) red[c] += red[c + s];
        __syncthreads();
    }
    float var = red[0] * (1.f / C_);
    float r = rsqrtf(var + 1e-6f);
    x1[(size_t)row * C_ + c] = x[(size_t)row * C_ + c] + d * r * g[c] + bta[c];
}

// ---------------- global context mean over N ----------------
__global__ void k_gctx(const float* __restrict__ x1, float* __restrict__ gctx) {
    int b = blockIdx.x, c = threadIdx.x;
    float acc = 0.f;
    for (int n = 0; n < N_; ++n) acc += x1[((size_t)(b * N_ + n)) * C_ + c];
    gctx[b * C_ + c] = acc * (1.f / N_);
}

// ---------------- gvec = gctx @ gi_w1 + gi_b1 ----------------
__global__ void k_gvec(const float* __restrict__ gctx, const float* __restrict__ w1,
                       const float* __restrict__ b1, float* __restrict__ gvec) {
    int b = blockIdx.x, j = threadIdx.x;
    __shared__ float sg[C_];
    sg[j] = gctx[b * C_ + j];
    __syncthreads();
    float acc = b1[j];
    for (int c = 0; c < C_; ++c) acc = fmaf(sg[c], w1[c * C_ + j], acc);
    gvec[b * C_ + j] = acc;
}

// ---------------- plain copy ----------------
__global__ void k_copy(const float* __restrict__ src, float* __restrict__ dst, int n) {
    int i = blockIdx.x * blockDim.x + threadIdx.x;
    if (i < n) dst[i] = src[i];
}

extern "C" void kernel_launch(void* const* d_in, const int* in_sizes, int n_in,
                              void* d_out, int out_size, void* d_ws, size_t ws_size,
                              hipStream_t stream) {
    const float* x      = (const float*)d_in[0];
    const float* coords = (const float*)d_in[1];
    const float* dwk    = (const float*)d_in[2];
    const float* dwb    = (const float*)d_in[3];
    const float* pw_w   = (const float*)d_in[4];
    const float* pw_b   = (const float*)d_in[5];
    const float* ln_g   = (const float*)d_in[6];
    const float* ln_b   = (const float*)d_in[7];
    const float* gi_w1  = (const float*)d_in[8];
    const float* gi_b1  = (const float*)d_in[9];
    const float* gi_w2  = (const float*)d_in[10];
    const float* gi_b2  = (const float*)d_in[11];
    const float* bn0g = (const float*)d_in[12], *bn0b = (const float*)d_in[13];
    const float* bn0m = (const float*)d_in[14], *bn0v = (const float*)d_in[15];
    const float* bn1g = (const float*)d_in[16], *bn1b = (const float*)d_in[17];
    const float* bn1m = (const float*)d_in[18], *bn1v = (const float*)d_in[19];
    const float* bn2g = (const float*)d_in[20], *bn2b = (const float*)d_in[21];
    const float* bn2m = (const float*)d_in[22], *bn2v = (const float*)d_in[23];
    const float* w_ff1 = (const float*)d_in[24];
    const float* b_ff1 = (const float*)d_in[25];
    const float* w_ff2 = (const float*)d_in[26];
    const float* b_ff2 = (const float*)d_in[27];

    char* ws = (char*)d_ws;
    int*   ge   = (int*)(ws + 0);
    int*   gp   = (int*)(ws + 32768);
    float* gctx = (float*)(ws + 65536);
    float* gvec = (float*)(ws + 98304);
    float* bnsh = (float*)(ws + 131072);          // 6*256 floats
    float* bufA = (float*)(ws + 262144);          // 8 MB  (t0, later x1)
    float* bufB = (float*)(ws + 262144 + 8388608);       // 8 MB  (h, later x2)
    float* bufU = (float*)(ws + 262144 + 2 * 8388608);   // 32 MB (ffn hidden)
    float* outx = (float*)d_out;

    const int M = B_ * N_;  // 8192

    k_grid_idx<<<B_, N_, 0, stream>>>(coords, ge, gp);
    k_bnprep<<<1, 256, 0, stream>>>(bn0g, bn0b, bn0m, bn0v,
                                    bn1g, bn1b, bn1m, bn1v,
                                    bn2g, bn2b, bn2m, bn2v, bnsh);
    k_cpe<<<M, C_, 0, stream>>>(x, ge, gp, dwk, dwb, bufA);

    // h = t0 @ pw_w + pw_b
    k_gemm<0><<<dim3(C_ / 64, M / 64), 256, 0, stream>>>(
        bufA, pw_w, pw_b, bufB, M, C_, C_,
        nullptr, nullptr, nullptr, nullptr, nullptr, nullptr);

    // x1 = x + LN(h)
    k_ln_resid<<<M, C_, 0, stream>>>(bufB, x, ln_g, ln_b, bufA);

    k_gctx<<<B_, C_, 0, stream>>>(bufA, gctx);
    k_gvec<<<B_, C_, 0, stream>>>(gctx, gi_w1, gi_b1, gvec);

    // x2 = bn1(x1 + bn0(x1@gi_w2 + gi_b2 + gvec))
    k_gemm<2><<<dim3(C_ / 64, M / 64), 256, 0, stream>>>(
        bufA, gi_w2, gi_b2, bufB, M, C_, C_,
        bufA, gvec, bnsh, bnsh + 256, bnsh + 512, bnsh + 768);

    // u = relu(x2 @ w_ff1 + b_ff1)
    k_gemm<1><<<dim3(DFF_ / 64, M / 64), 256, 0, stream>>>(
        bufB, w_ff1, b_ff1, bufU, M, DFF_, C_,
        nullptr, nullptr, nullptr, nullptr, nullptr, nullptr);

    // out = bn2(x2 + u @ w_ff2 + b_ff2)
    k_gemm<3><<<dim3(C_ / 64, M / 64), 256, 0, stream>>>(
        bufU, w_ff2, b_ff2, outx, M, C_, DFF_,
        bufB, nullptr, bnsh + 1024, bnsh + 1280, nullptr, nullptr);

    // second output: coords passthrough
    k_copy<<<(M * 2 + 255) / 256, 256, 0, stream>>>(coords, outx + (size_t)M * C_, M * 2);
}

// Round 2
// 121.100 us; speedup vs baseline: 2.5571x; 2.5571x over previous
//
#include <hip/hip_runtime.h>
#include <cstdint>
#include <cstddef>

#define B_   32
#define N_   256
#define C_   256
#define DFF_ 1024

typedef __attribute__((ext_vector_type(8))) short bf16x8;
typedef __attribute__((ext_vector_type(4))) float f32x4;

__device__ __forceinline__ unsigned short f2bf(float f) {
    unsigned u = __builtin_bit_cast(unsigned, f);
    u += 0x7FFFu + ((u >> 16) & 1u);
    return (unsigned short)(u >> 16);
}
__device__ __forceinline__ float bf2f(unsigned short b) {
    return __builtin_bit_cast(float, (unsigned)b << 16);
}

// swizzle: physical = logical ^ ((row&7)<<4); bits 4-6 mixed, bijective
__device__ __forceinline__ unsigned swz(unsigned a) {
    return a ^ (((a >> 6) & 7u) << 4);
}
// inverse (logical from physical)
__device__ __forceinline__ unsigned unswz(unsigned P) {
    unsigned L6 = ((P >> 6) ^ (P >> 8)) & 1u;
    unsigned L5 = ((P >> 5) ^ (P >> 7)) & 1u;
    unsigned L4 = (((P >> 4) & 1u) ^ L6);
    return (P & ~0x70u) | (L6 << 6) | (L5 << 5) | (L4 << 4);
}

// ---------------- geo: per-batch grid cells + neighbor lists ----------------
__global__ void k_geo(const float* __restrict__ coords,
                      unsigned short* __restrict__ nbr, int* __restrict__ ncnt) {
    int b = blockIdx.x, n = threadIdx.x;
    __shared__ float se[N_], sp[N_];
    __shared__ int sge[N_], sgp[N_];
    float eta = coords[(b * N_ + n) * 2 + 0];
    float phi = coords[(b * N_ + n) * 2 + 1];
    se[n] = eta; sp[n] = phi;
    __syncthreads();
    for (int s = 128; s > 0; s >>= 1) {
        if (n < s) {
            se[n] = fminf(se[n], se[n + s]);
            sp[n] = fminf(sp[n], sp[n + s]);
        }
        __syncthreads();
    }
    float emin = se[0], pmin = sp[0];
    int gi = (int)((eta - emin) / 0.1f); gi = gi < 0 ? 0 : (gi > 127 ? 127 : gi);
    int pi = (int)((phi - pmin) / 0.1f); pi = pi < 0 ? 0 : (pi > 127 ? 127 : pi);
    sge[n] = gi; sgp[n] = pi;
    __syncthreads();
    int cnt = 0;
    unsigned short* out = nbr + ((size_t)b * N_ + n) * N_;
    for (int m = 0; m < N_; ++m) {
        int dh = sge[m] - gi + 3;
        int dv = sgp[m] - pi + 3;
        if (((unsigned)dh < 8u) && ((unsigned)dv < 8u))
            out[cnt++] = (unsigned short)(m | ((dh * 8 + dv) << 8));
    }
    ncnt[b * N_ + n] = cnt;
}

// ---------------- CPE gather over neighbor list ----------------
__global__ void k_cpe2(const float* __restrict__ x,
                       const unsigned short* __restrict__ nbr, const int* __restrict__ ncnt,
                       const float* __restrict__ dwk, const float* __restrict__ dwb,
                       unsigned short* __restrict__ t0) {
    int bn = blockIdx.x;
    int b = bn >> 8;
    int c = threadIdx.x;
    __shared__ unsigned short sn[N_];
    int cnt = ncnt[bn];
    if (c < cnt) sn[c] = nbr[(size_t)bn * N_ + c];
    __syncthreads();
    const float* xb = x + (size_t)b * N_ * C_;
    float acc = dwb[c];
    for (int i = 0; i < cnt; ++i) {
        int pk = sn[i];
        int m = pk & 255, kid = pk >> 8;
        acc = fmaf(dwk[kid * C_ + c], xb[m * C_ + c], acc);
    }
    t0[(size_t)bn * C_ + c] = f2bf(acc);
}

// ---------------- BN inference scale/shift precompute ----------------
__global__ void k_bnprep(const float* g0, const float* b0, const float* m0, const float* v0,
                         const float* g1, const float* b1, const float* m1, const float* v1,
                         const float* g2, const float* b2, const float* m2, const float* v2,
                         float* __restrict__ sh) {
    int c = threadIdx.x;
    float s;
    s = g0[c] * rsqrtf(v0[c] + 1e-3f); sh[c]        = s; sh[256 + c]  = b0[c] - m0[c] * s;
    s = g1[c] * rsqrtf(v1[c] + 1e-3f); sh[512 + c]  = s; sh[768 + c]  = b1[c] - m1[c] * s;
    s = g2[c] * rsqrtf(v2[c] + 1e-3f); sh[1024 + c] = s; sh[1280 + c] = b2[c] - m2[c] * s;
}

// -------- weight prep: transpose [K][N] fp32 -> [N][K] bf16, 4 matrices ------
__global__ void k_wprep(const float* __restrict__ pw, const float* __restrict__ gi,
                        const float* __restrict__ ff1, const float* __restrict__ ff2,
                        unsigned short* __restrict__ tpw, unsigned short* __restrict__ tgi,
                        unsigned short* __restrict__ tff1, unsigned short* __restrict__ tff2) {
    __shared__ float s[32][33];
    int bid = blockIdx.x;
    const float* W; unsigned short* T; int K, Nn, t;
    if (bid < 64)       { W = pw;  T = tpw;  K = 256;  Nn = 256;  t = bid; }
    else if (bid < 128) { W = gi;  T = tgi;  K = 256;  Nn = 256;  t = bid - 64; }
    else if (bid < 384) { W = ff1; T = tff1; K = 256;  Nn = 1024; t = bid - 128; }
    else                { W = ff2; T = tff2; K = 1024; Nn = 256;  t = bid - 384; }
    int ntiles_n = Nn >> 5;
    int n0 = (t % ntiles_n) << 5, k0 = (t / ntiles_n) << 5;
    int tx = threadIdx.x & 31, ty = threadIdx.x >> 5;
    #pragma unroll
    for (int j = 0; j < 4; ++j)
        s[ty + j * 8][tx] = W[(size_t)(k0 + ty + j * 8) * Nn + n0 + tx];
    __syncthreads();
    #pragma unroll
    for (int j = 0; j < 4; ++j)
        T[(size_t)(n0 + ty + j * 8) * K + k0 + tx] = f2bf(s[tx][ty + j * 8]);
}

// ---------------- bf16 MFMA GEMM, 64x64 tile, BK=32, fused epilogues ----------
// EPI 0: Cb = bf16(acc + bias)
// EPI 1: Cb = bf16(relu(acc + bias))
// EPI 2: v=acc+bias+gvec[b,col]; v=v*s0+h0; v=(residf+v)*s1+h1; Cb=bf16(v), Cf=v
// EPI 3: v=acc+bias; v=(residf+v)*s0+h0; Cf=v
template <int EPI>
__global__ __launch_bounds__(256) void k_mgemm(
    const unsigned short* __restrict__ A, const unsigned short* __restrict__ Wt,
    const float* __restrict__ bias, int M, int Nn, int K,
    unsigned short* __restrict__ Cb, float* __restrict__ Cf,
    const float* __restrict__ residf, const float* __restrict__ gvec,
    const float* __restrict__ s0, const float* __restrict__ h0,
    const float* __restrict__ s1, const float* __restrict__ h1) {
    __shared__ unsigned short sA[2048];   // 64 rows x 32 k, bf16, swizzled
    __shared__ unsigned short sB[2048];
    int tid = threadIdx.x;
    int lane = tid & 63, wv = tid >> 6;
    int rowBase = blockIdx.y * 64, colBase = blockIdx.x * 64;

    // staging: linear LDS dest (wave base + lane*16), inverse-swizzled global src
    unsigned P = (unsigned)tid * 16;
    unsigned L = unswz(P);
    unsigned srow = L >> 6, skk = (L >> 1) & 31u;
    const unsigned short* srcA0 = A  + (size_t)(rowBase + srow) * K + skk;
    const unsigned short* srcB0 = Wt + (size_t)(colBase + srow) * K + skk;
    char* dstA = (char*)sA + wv * 1024;
    char* dstB = (char*)sB + wv * 1024;

    int wr = (wv >> 1) * 32, wc = (wv & 1) * 32;
    int l16 = lane & 15, g = lane >> 4;
    unsigned offA0 = swz((unsigned)((wr + l16) * 64 + g * 16));
    unsigned offA1 = swz((unsigned)((wr + 16 + l16) * 64 + g * 16));
    unsigned offB0 = swz((unsigned)((wc + l16) * 64 + g * 16));
    unsigned offB1 = swz((unsigned)((wc + 16 + l16) * 64 + g * 16));

    f32x4 acc00 = {0.f, 0.f, 0.f, 0.f}, acc01 = {0.f, 0.f, 0.f, 0.f};
    f32x4 acc10 = {0.f, 0.f, 0.f, 0.f}, acc11 = {0.f, 0.f, 0.f, 0.f};

    for (int k0 = 0; k0 < K; k0 += 32) {
        __builtin_amdgcn_global_load_lds(
            (const __attribute__((address_space(1))) void*)(srcA0 + k0),
            (__attribute__((address_space(3))) void*)dstA, 16, 0, 0);
        __builtin_amdgcn_global_load_lds(
            (const __attribute__((address_space(1))) void*)(srcB0 + k0),
            (__attribute__((address_space(3))) void*)dstB, 16, 0, 0);
        asm volatile("s_waitcnt vmcnt(0)" ::: "memory");
        __syncthreads();
        bf16x8 a0 = *(const bf16x8*)((const char*)sA + offA0);
        bf16x8 a1 = *(const bf16x8*)((const char*)sA + offA1);
        bf16x8 b0 = *(const bf16x8*)((const char*)sB + offB0);
        bf16x8 b1 = *(const bf16x8*)((const char*)sB + offB1);
        acc00 = __builtin_amdgcn_mfma_f32_16x16x32_bf16(a0, b0, acc00, 0, 0, 0);
        acc01 = __builtin_amdgcn_mfma_f32_16x16x32_bf16(a0, b1, acc01, 0, 0, 0);
        acc10 = __builtin_amdgcn_mfma_f32_16x16x32_bf16(a1, b0, acc10, 0, 0, 0);
        acc11 = __builtin_amdgcn_mfma_f32_16x16x32_bf16(a1, b1, acc11, 0, 0, 0);
        __syncthreads();
    }

    // epilogue: C/D layout col=lane&15, row=(lane>>4)*4+reg
    #pragma unroll
    for (int mi = 0; mi < 2; ++mi) {
        int rbase = rowBase + wr + mi * 16 + g * 4;
        #pragma unroll
        for (int ni = 0; ni < 2; ++ni) {
            f32x4 av = (mi == 0) ? ((ni == 0) ? acc00 : acc01)
                                 : ((ni == 0) ? acc10 : acc11);
            int col = colBase + wc + ni * 16 + l16;
            #pragma unroll
            for (int j = 0; j < 4; ++j) {
                int row = rbase + j;
                float v = av[j] + bias[col];
                size_t oidx = (size_t)row * Nn + col;
                if constexpr (EPI == 0) {
                    Cb[oidx] = f2bf(v);
                } else if constexpr (EPI == 1) {
                    v = fmaxf(v, 0.f);
                    Cb[oidx] = f2bf(v);
                } else if constexpr (EPI == 2) {
                    v += gvec[(row >> 8) * C_ + col];
                    v = v * s0[col] + h0[col];
                    float xv = residf[oidx];
                    v = (xv + v) * s1[col] + h1[col];
                    Cb[oidx] = f2bf(v);
                    Cf[oidx] = v;
                } else {
                    float xv = residf[oidx];
                    v = (xv + v) * s0[col] + h0[col];
                    Cf[oidx] = v;
                }
            }
        }
    }
}

// ---------------- x1 = x + LN(h); one wave per row ----------------
__global__ void k_ln(const unsigned short* __restrict__ hb, const float* __restrict__ x,
                     const float* __restrict__ g, const float* __restrict__ bta,
                     float* __restrict__ x1f, unsigned short* __restrict__ x1b) {
    int row = blockIdx.x * 4 + (threadIdx.x >> 6);
    int lane = threadIdx.x & 63;
    int c = lane * 4;
    ushort4 hv = *(const ushort4*)(hb + (size_t)row * C_ + c);
    float v0 = bf2f(hv.x), v1 = bf2f(hv.y), v2 = bf2f(hv.z), v3 = bf2f(hv.w);
    float s = v0 + v1 + v2 + v3;
    #pragma unroll
    for (int m = 1; m < 64; m <<= 1) s += __shfl_xor(s, m);
    float mu = s * (1.f / 256.f);
    float d0 = v0 - mu, d1 = v1 - mu, d2 = v2 - mu, d3 = v3 - mu;
    float q = d0 * d0 + d1 * d1 + d2 * d2 + d3 * d3;
    #pragma unroll
    for (int m = 1; m < 64; m <<= 1) q += __shfl_xor(q, m);
    float r = rsqrtf(q * (1.f / 256.f) + 1e-6f);
    float4 xv = *(const float4*)(x + (size_t)row * C_ + c);
    float o0 = xv.x + d0 * r * g[c + 0] + bta[c + 0];
    float o1 = xv.y + d1 * r * g[c + 1] + bta[c + 1];
    float o2 = xv.z + d2 * r * g[c + 2] + bta[c + 2];
    float o3 = xv.w + d3 * r * g[c + 3] + bta[c + 3];
    *(float4*)(x1f + (size_t)row * C_ + c) = make_float4(o0, o1, o2, o3);
    ushort4 ob; ob.x = f2bf(o0); ob.y = f2bf(o1); ob.z = f2bf(o2); ob.w = f2bf(o3);
    *(ushort4*)(x1b + (size_t)row * C_ + c) = ob;
}

// ---------------- global context mean over N ----------------
__global__ void k_gctx(const float* __restrict__ x1f, float* __restrict__ gctx) {
    int b = blockIdx.x, c = threadIdx.x;
    const float* p = x1f + (size_t)b * N_ * C_ + c;
    float acc = 0.f;
    for (int n = 0; n < N_; ++n) acc += p[n * C_];
    gctx[b * C_ + c] = acc * (1.f / N_);
}

// ---------------- gvec = gctx @ gi_w1 + gi_b1 ----------------
__global__ void k_gvec(const float* __restrict__ gctx, const float* __restrict__ w1,
                       const float* __restrict__ b1, float* __restrict__ gvec) {
    int b = blockIdx.x, j = threadIdx.x;
    __shared__ float sg[C_];
    sg[j] = gctx[b * C_ + j];
    __syncthreads();
    float acc = b1[j];
    for (int c = 0; c < C_; ++c) acc = fmaf(sg[c], w1[c * C_ + j], acc);
    gvec[b * C_ + j] = acc;
}

// ---------------- plain copy ----------------
__global__ void k_copy(const float* __restrict__ src, float* __restrict__ dst, int n) {
    int i = blockIdx.x * blockDim.x + threadIdx.x;
    if (i < n) dst[i] = src[i];
}

extern "C" void kernel_launch(void* const* d_in, const int* in_sizes, int n_in,
                              void* d_out, int out_size, void* d_ws, size_t ws_size,
                              hipStream_t stream) {
    const float* x      = (const float*)d_in[0];
    const float* coords = (const float*)d_in[1];
    const float* dwk    = (const float*)d_in[2];
    const float* dwb    = (const float*)d_in[3];
    const float* pw_w   = (const float*)d_in[4];
    const float* pw_b   = (const float*)d_in[5];
    const float* ln_g   = (const float*)d_in[6];
    const float* ln_b   = (const float*)d_in[7];
    const float* gi_w1  = (const float*)d_in[8];
    const float* gi_b1  = (const float*)d_in[9];
    const float* gi_w2  = (const float*)d_in[10];
    const float* gi_b2  = (const float*)d_in[11];
    const float* bn0g = (const float*)d_in[12], *bn0b = (const float*)d_in[13];
    const float* bn0m = (const float*)d_in[14], *bn0v = (const float*)d_in[15];
    const float* bn1g = (const float*)d_in[16], *bn1b = (const float*)d_in[17];
    const float* bn1m = (const float*)d_in[18], *bn1v = (const float*)d_in[19];
    const float* bn2g = (const float*)d_in[20], *bn2b = (const float*)d_in[21];
    const float* bn2m = (const float*)d_in[22], *bn2v = (const float*)d_in[23];
    const float* w_ff1 = (const float*)d_in[24];
    const float* b_ff1 = (const float*)d_in[25];
    const float* w_ff2 = (const float*)d_in[26];
    const float* b_ff2 = (const float*)d_in[27];

    char* ws = (char*)d_ws;
    int*            ncnt  = (int*)(ws + 0);
    float*          gctx  = (float*)(ws + 32768);
    float*          gvec  = (float*)(ws + 65536);
    float*          bnsh  = (float*)(ws + 98304);
    unsigned short* WtPW  = (unsigned short*)(ws + 131072);
    unsigned short* WtGI  = (unsigned short*)(ws + 262144);
    unsigned short* WtF1  = (unsigned short*)(ws + 393216);
    unsigned short* WtF2  = (unsigned short*)(ws + 917504);
    unsigned short* nbr   = (unsigned short*)(ws + 1441792);   // 4 MB
    unsigned short* bufT  = (unsigned short*)(ws + 5636096);   // 4 MB: t0, then x1_bf
    unsigned short* bufH  = (unsigned short*)(ws + 9830400);   // 4 MB: h,  then x2_bf
    float*          x1f   = (float*)(ws + 14024704);           // 8 MB
    float*          x2f   = (float*)(ws + 22413312);           // 8 MB
    unsigned short* u_b   = (unsigned short*)(ws + 30801920);  // 16 MB
    float*          outx  = (float*)d_out;

    const int M = B_ * N_;  // 8192

    k_geo<<<B_, N_, 0, stream>>>(coords, nbr, ncnt);
    k_bnprep<<<1, 256, 0, stream>>>(bn0g, bn0b, bn0m, bn0v,
                                    bn1g, bn1b, bn1m, bn1v,
                                    bn2g, bn2b, bn2m, bn2v, bnsh);
    k_wprep<<<640, 256, 0, stream>>>(pw_w, gi_w2, w_ff1, w_ff2, WtPW, WtGI, WtF1, WtF2);
    k_cpe2<<<M, C_, 0, stream>>>(x, nbr, ncnt, dwk, dwb, bufT);

    // h = t0 @ pw_w + pw_b  (bf16 out)
    k_mgemm<0><<<dim3(C_ / 64, M / 64), 256, 0, stream>>>(
        bufT, WtPW, pw_b, M, C_, C_, bufH, nullptr,
        nullptr, nullptr, nullptr, nullptr, nullptr, nullptr);

    // x1 = x + LN(h)   (fp32 + bf16 copies)
    k_ln<<<M / 4, 256, 0, stream>>>(bufH, x, ln_g, ln_b, x1f, bufT);

    k_gctx<<<B_, 256, 0, stream>>>(x1f, gctx);
    k_gvec<<<B_, 256, 0, stream>>>(gctx, gi_w1, gi_b1, gvec);

    // x2 = bn1(x1 + bn0(x1@gi_w2 + gi_b2 + gvec))
    k_mgemm<2><<<dim3(C_ / 64, M / 64), 256, 0, stream>>>(
        bufT, WtGI, gi_b2, M, C_, C_, bufH, x2f,
        x1f, gvec, bnsh, bnsh + 256, bnsh + 512, bnsh + 768);

    // u = relu(x2 @ w_ff1 + b_ff1)
    k_mgemm<1><<<dim3(DFF_ / 64, M / 64), 256, 0, stream>>>(
        bufH, WtF1, b_ff1, M, DFF_, C_, u_b, nullptr,
        nullptr, nullptr, nullptr, nullptr, nullptr, nullptr);

    // out = bn2(x2 + u @ w_ff2 + b_ff2)
    k_mgemm<3><<<dim3(C_ / 64, M / 64), 256, 0, stream>>>(
        u_b, WtF2, b_ff2, M, C_, DFF_, nullptr, outx,
        x2f, nullptr, bnsh + 1024, bnsh + 1280, nullptr, nullptr);

    // second output: coords passthrough
    k_copy<<<(M * 2 + 255) / 256, 256, 0, stream>>>(coords, outx + (size_t)M * C_, M * 2);
}

// Round 3
// 116.272 us; speedup vs baseline: 2.6633x; 1.0415x over previous
//
#include <hip/hip_runtime.h>
#include <cstdint>
#include <cstddef>

#define B_   32
#define N_   256
#define C_   256
#define DFF_ 1024

typedef __attribute__((ext_vector_type(8))) short bf16x8;
typedef __attribute__((ext_vector_type(4))) float f32x4;

__device__ __forceinline__ unsigned short f2bf(float f) {
    unsigned u = __builtin_bit_cast(unsigned, f);
    u += 0x7FFFu + ((u >> 16) & 1u);
    return (unsigned short)(u >> 16);
}
__device__ __forceinline__ float bf2f(unsigned short b) {
    return __builtin_bit_cast(float, (unsigned)b << 16);
}

// BK=64 swizzle: row at bits 7+, XOR bits 4-6 with row&7 -> involution (self-inverse)
__device__ __forceinline__ unsigned swz64(unsigned a) {
    return a ^ (((a >> 7) & 7u) << 4);
}

#define GLL(src, dst) __builtin_amdgcn_global_load_lds( \
    (const __attribute__((address_space(1))) void*)(src), \
    (__attribute__((address_space(3))) void*)(dst), 16, 0, 0)

// ---- geo: grid cells + neighbor lists; block 32 = bnprep; coords copy fused ----
__global__ void k_geo(const float* __restrict__ coords,
                      unsigned short* __restrict__ nbr, int* __restrict__ ncnt,
                      const float* g0, const float* b0, const float* m0, const float* v0,
                      const float* g1, const float* b1, const float* m1, const float* v1,
                      const float* g2, const float* b2, const float* m2, const float* v2,
                      float* __restrict__ sh, float* __restrict__ coords_out) {
    int b = blockIdx.x;
    int n = threadIdx.x;
    if (b == B_) {  // BN scale/shift precompute
        int c = n;
        float s;
        s = g0[c] * rsqrtf(v0[c] + 1e-3f); sh[c]        = s; sh[256 + c]  = b0[c] - m0[c] * s;
        s = g1[c] * rsqrtf(v1[c] + 1e-3f); sh[512 + c]  = s; sh[768 + c]  = b1[c] - m1[c] * s;
        s = g2[c] * rsqrtf(v2[c] + 1e-3f); sh[1024 + c] = s; sh[1280 + c] = b2[c] - m2[c] * s;
        return;
    }
    __shared__ float se[N_], sp[N_];
    __shared__ int sge[N_], sgp[N_];
    float eta = coords[(b * N_ + n) * 2 + 0];
    float phi = coords[(b * N_ + n) * 2 + 1];
    // coords passthrough output
    coords_out[b * 512 + n] = coords[b * 512 + n];
    coords_out[b * 512 + 256 + n] = coords[b * 512 + 256 + n];
    se[n] = eta; sp[n] = phi;
    __syncthreads();
    for (int s = 128; s > 0; s >>= 1) {
        if (n < s) {
            se[n] = fminf(se[n], se[n + s]);
            sp[n] = fminf(sp[n], sp[n + s]);
        }
        __syncthreads();
    }
    float emin = se[0], pmin = sp[0];
    int gi = (int)((eta - emin) / 0.1f); gi = gi < 0 ? 0 : (gi > 127 ? 127 : gi);
    int pi = (int)((phi - pmin) / 0.1f); pi = pi < 0 ? 0 : (pi > 127 ? 127 : pi);
    sge[n] = gi; sgp[n] = pi;
    __syncthreads();
    int cnt = 0;
    unsigned short* out = nbr + ((size_t)b * N_ + n) * N_;
    for (int m = 0; m < N_; ++m) {
        int dh = sge[m] - gi + 3;
        int dv = sgp[m] - pi + 3;
        if (((unsigned)dh < 8u) && ((unsigned)dv < 8u))
            out[cnt++] = (unsigned short)(m | ((dh * 8 + dv) << 8));
    }
    ncnt[b * N_ + n] = cnt;
}

// ---------------- CPE gather over neighbor list ----------------
__global__ void k_cpe2(const float* __restrict__ x,
                       const unsigned short* __restrict__ nbr, const int* __restrict__ ncnt,
                       const float* __restrict__ dwk, const float* __restrict__ dwb,
                       unsigned short* __restrict__ t0) {
    int bn = blockIdx.x;
    int b = bn >> 8;
    int c = threadIdx.x;
    __shared__ unsigned short sn[N_];
    int cnt = ncnt[bn];
    if (c < cnt) sn[c] = nbr[(size_t)bn * N_ + c];
    __syncthreads();
    const float* xb = x + (size_t)b * N_ * C_;
    float acc = dwb[c];
    for (int i = 0; i < cnt; ++i) {
        int pk = sn[i];
        int m = pk & 255, kid = pk >> 8;
        acc = fmaf(dwk[kid * C_ + c], xb[m * C_ + c], acc);
    }
    t0[(size_t)bn * C_ + c] = f2bf(acc);
}

// -------- weight prep: transpose [K][N] fp32 -> [N][K] bf16, 4 matrices ------
__global__ void k_wprep(const float* __restrict__ pw, const float* __restrict__ gi,
                        const float* __restrict__ ff1, const float* __restrict__ ff2,
                        unsigned short* __restrict__ tpw, unsigned short* __restrict__ tgi,
                        unsigned short* __restrict__ tff1, unsigned short* __restrict__ tff2) {
    __shared__ float s[32][33];
    int bid = blockIdx.x;
    const float* W; unsigned short* T; int K, Nn, t;
    if (bid < 64)       { W = pw;  T = tpw;  K = 256;  Nn = 256;  t = bid; }
    else if (bid < 128) { W = gi;  T = tgi;  K = 256;  Nn = 256;  t = bid - 64; }
    else if (bid < 384) { W = ff1; T = tff1; K = 256;  Nn = 1024; t = bid - 128; }
    else                { W = ff2; T = tff2; K = 1024; Nn = 256;  t = bid - 384; }
    int ntiles_n = Nn >> 5;
    int n0 = (t % ntiles_n) << 5, k0 = (t / ntiles_n) << 5;
    int tx = threadIdx.x & 31, ty = threadIdx.x >> 5;
    #pragma unroll
    for (int j = 0; j < 4; ++j)
        s[ty + j * 8][tx] = W[(size_t)(k0 + ty + j * 8) * Nn + n0 + tx];
    __syncthreads();
    #pragma unroll
    for (int j = 0; j < 4; ++j)
        T[(size_t)(n0 + ty + j * 8) * K + k0 + tx] = f2bf(s[tx][ty + j * 8]);
}

// ------- bf16 MFMA GEMM, 64x64 tile, BK=64, double-buffered, counted vmcnt ----
// EPI 0: Cb = bf16(acc + bias)
// EPI 1: Cb = bf16(relu(acc + bias))
// EPI 2: v=acc+bias+gvec[b,col]; v=v*s0+h0; v=(residf+v)*s1+h1; Cb=bf16(v), Cf=v
// EPI 3: v=acc+bias; v=(residf+v)*s0+h0; Cf=v
template <int EPI>
__global__ __launch_bounds__(256) void k_mgemm(
    const unsigned short* __restrict__ A, const unsigned short* __restrict__ Wt,
    const float* __restrict__ bias, int M, int Nn, int K,
    unsigned short* __restrict__ Cb, float* __restrict__ Cf,
    const float* __restrict__ residf, const float* __restrict__ gvec,
    const float* __restrict__ s0, const float* __restrict__ h0,
    const float* __restrict__ s1, const float* __restrict__ h1) {
    __shared__ __align__(16) unsigned short sA[2][4096];   // 64 rows x 64 k
    __shared__ __align__(16) unsigned short sB[2][4096];
    int tid = threadIdx.x;
    int lane = tid & 63, wv = tid >> 6;
    int rowBase = blockIdx.y * 64, colBase = blockIdx.x * 64;

    // staging: linear LDS dest (wave base + lane*16), involution-swizzled global src
    unsigned P0 = (unsigned)tid * 16, P1 = P0 + 4096;
    unsigned L0 = swz64(P0), L1 = swz64(P1);
    const unsigned short* aSrc0 = A  + (size_t)(rowBase + (L0 >> 7)) * K + ((L0 >> 1) & 63u);
    const unsigned short* aSrc1 = A  + (size_t)(rowBase + (L1 >> 7)) * K + ((L1 >> 1) & 63u);
    const unsigned short* bSrc0 = Wt + (size_t)(colBase + (L0 >> 7)) * K + ((L0 >> 1) & 63u);
    const unsigned short* bSrc1 = Wt + (size_t)(colBase + (L1 >> 7)) * K + ((L1 >> 1) & 63u);
    unsigned dO0 = (unsigned)wv * 1024, dO1 = dO0 + 4096;

    int wr = (wv >> 1) * 32, wc = (wv & 1) * 32;
    int l16 = lane & 15, g = lane >> 4;
    unsigned oA[2][2], oB[2][2];
    #pragma unroll
    for (int mi = 0; mi < 2; ++mi)
        #pragma unroll
        for (int kk = 0; kk < 2; ++kk) {
            oA[mi][kk] = swz64((unsigned)((wr + mi * 16 + l16) * 128 + kk * 64 + g * 16));
            oB[mi][kk] = swz64((unsigned)((wc + mi * 16 + l16) * 128 + kk * 64 + g * 16));
        }

    f32x4 acc[2][2] = {};
    int nt = K >> 6;

    GLL(aSrc0, (char*)sA[0] + dO0); GLL(aSrc1, (char*)sA[0] + dO1);
    GLL(bSrc0, (char*)sB[0] + dO0); GLL(bSrc1, (char*)sB[0] + dO1);
    int cur = 0;
    for (int t = 0; t < nt; ++t) {
        if (t + 1 < nt) {
            int o = (t + 1) << 6;
            GLL(aSrc0 + o, (char*)sA[cur ^ 1] + dO0); GLL(aSrc1 + o, (char*)sA[cur ^ 1] + dO1);
            GLL(bSrc0 + o, (char*)sB[cur ^ 1] + dO0); GLL(bSrc1 + o, (char*)sB[cur ^ 1] + dO1);
            asm volatile("s_waitcnt vmcnt(4)" ::: "memory");
        } else {
            asm volatile("s_waitcnt vmcnt(0)" ::: "memory");
        }
        __syncthreads();
        const char* cA = (const char*)sA[cur];
        const char* cB = (const char*)sB[cur];
        #pragma unroll
        for (int kk = 0; kk < 2; ++kk) {
            bf16x8 a0 = *(const bf16x8*)(cA + oA[0][kk]);
            bf16x8 a1 = *(const bf16x8*)(cA + oA[1][kk]);
            bf16x8 b0 = *(const bf16x8*)(cB + oB[0][kk]);
            bf16x8 b1 = *(const bf16x8*)(cB + oB[1][kk]);
            acc[0][0] = __builtin_amdgcn_mfma_f32_16x16x32_bf16(a0, b0, acc[0][0], 0, 0, 0);
            acc[0][1] = __builtin_amdgcn_mfma_f32_16x16x32_bf16(a0, b1, acc[0][1], 0, 0, 0);
            acc[1][0] = __builtin_amdgcn_mfma_f32_16x16x32_bf16(a1, b0, acc[1][0], 0, 0, 0);
            acc[1][1] = __builtin_amdgcn_mfma_f32_16x16x32_bf16(a1, b1, acc[1][1], 0, 0, 0);
        }
        __syncthreads();
        cur ^= 1;
    }

    // epilogue: C/D layout col=lane&15, row=(lane>>4)*4+reg
    #pragma unroll
    for (int mi = 0; mi < 2; ++mi) {
        int rbase = rowBase + wr + mi * 16 + g * 4;
        #pragma unroll
        for (int ni = 0; ni < 2; ++ni) {
            f32x4 av = acc[mi][ni];
            int col = colBase + wc + ni * 16 + l16;
            #pragma unroll
            for (int j = 0; j < 4; ++j) {
                int row = rbase + j;
                float v = av[j] + bias[col];
                size_t oidx = (size_t)row * Nn + col;
                if constexpr (EPI == 0) {
                    Cb[oidx] = f2bf(v);
                } else if constexpr (EPI == 1) {
                    v = fmaxf(v, 0.f);
                    Cb[oidx] = f2bf(v);
                } else if constexpr (EPI == 2) {
                    v += gvec[(row >> 8) * C_ + col];
                    v = v * s0[col] + h0[col];
                    float xv = residf[oidx];
                    v = (xv + v) * s1[col] + h1[col];
                    Cb[oidx] = f2bf(v);
                    Cf[oidx] = v;
                } else {
                    float xv = residf[oidx];
                    v = (xv + v) * s0[col] + h0[col];
                    Cf[oidx] = v;
                }
            }
        }
    }
}

// ---------------- x1 = x + LN(h); one wave per row ----------------
__global__ void k_ln(const unsigned short* __restrict__ hb, const float* __restrict__ x,
                     const float* __restrict__ g, const float* __restrict__ bta,
                     float* __restrict__ x1f, unsigned short* __restrict__ x1b) {
    int row = blockIdx.x * 4 + (threadIdx.x >> 6);
    int lane = threadIdx.x & 63;
    int c = lane * 4;
    ushort4 hv = *(const ushort4*)(hb + (size_t)row * C_ + c);
    float v0 = bf2f(hv.x), v1 = bf2f(hv.y), v2 = bf2f(hv.z), v3 = bf2f(hv.w);
    float s = v0 + v1 + v2 + v3;
    #pragma unroll
    for (int m = 1; m < 64; m <<= 1) s += __shfl_xor(s, m);
    float mu = s * (1.f / 256.f);
    float d0 = v0 - mu, d1 = v1 - mu, d2 = v2 - mu, d3 = v3 - mu;
    float q = d0 * d0 + d1 * d1 + d2 * d2 + d3 * d3;
    #pragma unroll
    for (int m = 1; m < 64; m <<= 1) q += __shfl_xor(q, m);
    float r = rsqrtf(q * (1.f / 256.f) + 1e-6f);
    float4 xv = *(const float4*)(x + (size_t)row * C_ + c);
    float o0 = xv.x + d0 * r * g[c + 0] + bta[c + 0];
    float o1 = xv.y + d1 * r * g[c + 1] + bta[c + 1];
    float o2 = xv.z + d2 * r * g[c + 2] + bta[c + 2];
    float o3 = xv.w + d3 * r * g[c + 3] + bta[c + 3];
    *(float4*)(x1f + (size_t)row * C_ + c) = make_float4(o0, o1, o2, o3);
    ushort4 ob; ob.x = f2bf(o0); ob.y = f2bf(o1); ob.z = f2bf(o2); ob.w = f2bf(o3);
    *(ushort4*)(x1b + (size_t)row * C_ + c) = ob;
}

// ------------- gctx = mean over N, then gvec = gctx @ gi_w1 + gi_b1 -----------
__global__ void k_gctxvec(const float* __restrict__ x1f, const float* __restrict__ w1,
                          const float* __restrict__ b1, float* __restrict__ gvec) {
    int b = blockIdx.x, j = threadIdx.x;
    __shared__ float sg[C_];
    const float* p = x1f + (size_t)b * N_ * C_ + j;
    float acc = 0.f;
    #pragma unroll 8
    for (int n = 0; n < N_; ++n) acc += p[n * C_];
    sg[j] = acc * (1.f / N_);
    __syncthreads();
    float a2 = b1[j];
    #pragma unroll 8
    for (int c = 0; c < C_; ++c) a2 = fmaf(sg[c], w1[c * C_ + j], a2);
    gvec[b * C_ + j] = a2;
}

extern "C" void kernel_launch(void* const* d_in, const int* in_sizes, int n_in,
                              void* d_out, int out_size, void* d_ws, size_t ws_size,
                              hipStream_t stream) {
    const float* x      = (const float*)d_in[0];
    const float* coords = (const float*)d_in[1];
    const float* dwk    = (const float*)d_in[2];
    const float* dwb    = (const float*)d_in[3];
    const float* pw_w   = (const float*)d_in[4];
    const float* pw_b   = (const float*)d_in[5];
    const float* ln_g   = (const float*)d_in[6];
    const float* ln_b   = (const float*)d_in[7];
    const float* gi_w1  = (const float*)d_in[8];
    const float* gi_b1  = (const float*)d_in[9];
    const float* gi_w2  = (const float*)d_in[10];
    const float* gi_b2  = (const float*)d_in[11];
    const float* bn0g = (const float*)d_in[12], *bn0b = (const float*)d_in[13];
    const float* bn0m = (const float*)d_in[14], *bn0v = (const float*)d_in[15];
    const float* bn1g = (const float*)d_in[16], *bn1b = (const float*)d_in[17];
    const float* bn1m = (const float*)d_in[18], *bn1v = (const float*)d_in[19];
    const float* bn2g = (const float*)d_in[20], *bn2b = (const float*)d_in[21];
    const float* bn2m = (const float*)d_in[22], *bn2v = (const float*)d_in[23];
    const float* w_ff1 = (const float*)d_in[24];
    const float* b_ff1 = (const float*)d_in[25];
    const float* w_ff2 = (const float*)d_in[26];
    const float* b_ff2 = (const float*)d_in[27];

    char* ws = (char*)d_ws;
    int*            ncnt  = (int*)(ws + 0);
    float*          gvec  = (float*)(ws + 65536);
    float*          bnsh  = (float*)(ws + 98304);
    unsigned short* WtPW  = (unsigned short*)(ws + 131072);
    unsigned short* WtGI  = (unsigned short*)(ws + 262144);
    unsigned short* WtF1  = (unsigned short*)(ws + 393216);
    unsigned short* WtF2  = (unsigned short*)(ws + 917504);
    unsigned short* nbr   = (unsigned short*)(ws + 1441792);   // 4 MB
    unsigned short* bufT  = (unsigned short*)(ws + 5636096);   // 4 MB: t0, then x1_bf
    unsigned short* bufH  = (unsigned short*)(ws + 9830400);   // 4 MB: h,  then x2_bf
    float*          x1f   = (float*)(ws + 14024704);           // 8 MB
    float*          x2f   = (float*)(ws + 22413312);           // 8 MB
    unsigned short* u_b   = (unsigned short*)(ws + 30801920);  // 16 MB
    float*          outx  = (float*)d_out;

    const int M = B_ * N_;  // 8192

    // geo + bnprep (block 32) + coords passthrough
    k_geo<<<B_ + 1, N_, 0, stream>>>(coords, nbr, ncnt,
                                     bn0g, bn0b, bn0m, bn0v,
                                     bn1g, bn1b, bn1m, bn1v,
                                     bn2g, bn2b, bn2m, bn2v,
                                     bnsh, outx + (size_t)M * C_);
    k_wprep<<<640, 256, 0, stream>>>(pw_w, gi_w2, w_ff1, w_ff2, WtPW, WtGI, WtF1, WtF2);
    k_cpe2<<<M, C_, 0, stream>>>(x, nbr, ncnt, dwk, dwb, bufT);

    // h = t0 @ pw_w + pw_b  (bf16 out)
    k_mgemm<0><<<dim3(C_ / 64, M / 64), 256, 0, stream>>>(
        bufT, WtPW, pw_b, M, C_, C_, bufH, nullptr,
        nullptr, nullptr, nullptr, nullptr, nullptr, nullptr);

    // x1 = x + LN(h)   (fp32 + bf16 copies)
    k_ln<<<M / 4, 256, 0, stream>>>(bufH, x, ln_g, ln_b, x1f, bufT);

    // gvec = (mean_n x1) @ gi_w1 + gi_b1
    k_gctxvec<<<B_, 256, 0, stream>>>(x1f, gi_w1, gi_b1, gvec);

    // x2 = bn1(x1 + bn0(x1@gi_w2 + gi_b2 + gvec))
    k_mgemm<2><<<dim3(C_ / 64, M / 64), 256, 0, stream>>>(
        bufT, WtGI, gi_b2, M, C_, C_, bufH, x2f,
        x1f, gvec, bnsh, bnsh + 256, bnsh + 512, bnsh + 768);

    // u = relu(x2 @ w_ff1 + b_ff1)
    k_mgemm<1><<<dim3(DFF_ / 64, M / 64), 256, 0, stream>>>(
        bufH, WtF1, b_ff1, M, DFF_, C_, u_b, nullptr,
        nullptr, nullptr, nullptr, nullptr, nullptr, nullptr);

    // out = bn2(x2 + u @ w_ff2 + b_ff2)
    k_mgemm<3><<<dim3(C_ / 64, M / 64), 256, 0, stream>>>(
        u_b, WtF2, b_ff2, M, C_, DFF_, nullptr, outx,
        x2f, nullptr, bnsh + 1024, bnsh + 1280, nullptr, nullptr);
}

// Round 4
// 112.477 us; speedup vs baseline: 2.7532x; 1.0337x over previous
//
#include <hip/hip_runtime.h>
#include <cstdint>
#include <cstddef>

#define B_   32
#define N_   256
#define C_   256
#define DFF_ 1024

typedef unsigned short ushort_t;
typedef __attribute__((ext_vector_type(8))) short bf16x8;
typedef __attribute__((ext_vector_type(4))) float f32x4;

__device__ __forceinline__ ushort_t f2bf(float f) {
    unsigned u = __builtin_bit_cast(unsigned, f);
    u += 0x7FFFu + ((u >> 16) & 1u);
    return (ushort_t)(u >> 16);
}
__device__ __forceinline__ float bf2f(ushort_t b) {
    return __builtin_bit_cast(float, (unsigned)b << 16);
}

// BK=64 (128B rows): XOR byte-bits 4-6 with row bits 7-9 -> involution
__device__ __forceinline__ unsigned swz64(unsigned a) {
    return a ^ (((a >> 7) & 7u) << 4);
}

#define GLL(src, dst) __builtin_amdgcn_global_load_lds( \
    (const __attribute__((address_space(1))) void*)(src), \
    (__attribute__((address_space(3))) void*)(dst), 16, 0, 0)

// ---- geo: grid cells + neighbor lists; block 32 = bnprep; coords copy fused ----
__global__ void k_geo(const float* __restrict__ coords,
                      ushort_t* __restrict__ nbr, int* __restrict__ ncnt,
                      const float* g0, const float* b0, const float* m0, const float* v0,
                      const float* g1, const float* b1, const float* m1, const float* v1,
                      const float* g2, const float* b2, const float* m2, const float* v2,
                      float* __restrict__ sh, float* __restrict__ coords_out) {
    int b = blockIdx.x;
    int n = threadIdx.x;
    if (b == B_) {
        int c = n;
        float s;
        s = g0[c] * rsqrtf(v0[c] + 1e-3f); sh[c]        = s; sh[256 + c]  = b0[c] - m0[c] * s;
        s = g1[c] * rsqrtf(v1[c] + 1e-3f); sh[512 + c]  = s; sh[768 + c]  = b1[c] - m1[c] * s;
        s = g2[c] * rsqrtf(v2[c] + 1e-3f); sh[1024 + c] = s; sh[1280 + c] = b2[c] - m2[c] * s;
        return;
    }
    __shared__ float se[N_], sp[N_];
    __shared__ int sge[N_], sgp[N_];
    float eta = coords[(b * N_ + n) * 2 + 0];
    float phi = coords[(b * N_ + n) * 2 + 1];
    coords_out[b * 512 + n] = coords[b * 512 + n];
    coords_out[b * 512 + 256 + n] = coords[b * 512 + 256 + n];
    se[n] = eta; sp[n] = phi;
    __syncthreads();
    for (int s = 128; s > 0; s >>= 1) {
        if (n < s) {
            se[n] = fminf(se[n], se[n + s]);
            sp[n] = fminf(sp[n], sp[n + s]);
        }
        __syncthreads();
    }
    float emin = se[0], pmin = sp[0];
    int gi = (int)((eta - emin) / 0.1f); gi = gi < 0 ? 0 : (gi > 127 ? 127 : gi);
    int pi = (int)((phi - pmin) / 0.1f); pi = pi < 0 ? 0 : (pi > 127 ? 127 : pi);
    sge[n] = gi; sgp[n] = pi;
    __syncthreads();
    int cnt = 0;
    ushort_t* out = nbr + ((size_t)b * N_ + n) * N_;
    for (int m = 0; m < N_; ++m) {
        int dh = sge[m] - gi + 3;
        int dv = sgp[m] - pi + 3;
        if (((unsigned)dh < 8u) && ((unsigned)dv < 8u))
            out[cnt++] = (ushort_t)(m | ((dh * 8 + dv) << 8));
    }
    ncnt[b * N_ + n] = cnt;
}

// ---------------- CPE gather: one wave per point, float4 over channels --------
__global__ __launch_bounds__(256) void k_cpe2(
        const float* __restrict__ x,
        const ushort_t* __restrict__ nbr, const int* __restrict__ ncnt,
        const float* __restrict__ dwk, const float* __restrict__ dwb,
        ushort_t* __restrict__ t0) {
    int wv = threadIdx.x >> 6, lane = threadIdx.x & 63;
    int bn = blockIdx.x * 4 + wv;
    int b = bn >> 8;
    int c0 = lane * 4;
    int cnt = ncnt[bn];
    const ushort_t* lst = nbr + (size_t)bn * N_;
    float4 acc = *(const float4*)(dwb + c0);
    const float* xb = x + (size_t)b * N_ * C_;
    for (int i = 0; i < cnt; ++i) {
        int pk = lst[i];
        int m = pk & 255, kid = pk >> 8;
        float4 w = *(const float4*)(dwk + kid * C_ + c0);
        float4 v = *(const float4*)(xb + m * C_ + c0);
        acc.x = fmaf(w.x, v.x, acc.x);
        acc.y = fmaf(w.y, v.y, acc.y);
        acc.z = fmaf(w.z, v.z, acc.z);
        acc.w = fmaf(w.w, v.w, acc.w);
    }
    ushort4 ob; ob.x = f2bf(acc.x); ob.y = f2bf(acc.y); ob.z = f2bf(acc.z); ob.w = f2bf(acc.w);
    *(ushort4*)(t0 + (size_t)bn * C_ + c0) = ob;
}

// -------- weight prep: transpose [K][N] fp32 -> [N][K] bf16, 4 matrices ------
__global__ void k_wprep(const float* __restrict__ pw, const float* __restrict__ gi,
                        const float* __restrict__ ff1, const float* __restrict__ ff2,
                        ushort_t* __restrict__ tpw, ushort_t* __restrict__ tgi,
                        ushort_t* __restrict__ tff1, ushort_t* __restrict__ tff2) {
    __shared__ float s[32][33];
    int bid = blockIdx.x;
    const float* W; ushort_t* T; int K, Nn, t;
    if (bid < 64)       { W = pw;  T = tpw;  K = 256;  Nn = 256;  t = bid; }
    else if (bid < 128) { W = gi;  T = tgi;  K = 256;  Nn = 256;  t = bid - 64; }
    else if (bid < 384) { W = ff1; T = tff1; K = 256;  Nn = 1024; t = bid - 128; }
    else                { W = ff2; T = tff2; K = 1024; Nn = 256;  t = bid - 384; }
    int ntiles_n = Nn >> 5;
    int n0 = (t % ntiles_n) << 5, k0 = (t / ntiles_n) << 5;
    int tx = threadIdx.x & 31, ty = threadIdx.x >> 5;
    #pragma unroll
    for (int j = 0; j < 4; ++j)
        s[ty + j * 8][tx] = W[(size_t)(k0 + ty + j * 8) * Nn + n0 + tx];
    __syncthreads();
    #pragma unroll
    for (int j = 0; j < 4; ++j)
        T[(size_t)(n0 + ty + j * 8) * K + k0 + tx] = f2bf(s[tx][ty + j * 8]);
}

// ---- full-row GEMM: BM=32, BN=256, BK=64, 4 waves (each 32x64 cols slice) ----
// EPI 4: h=acc+bias; LN over 256 cols; out = resid + LN*g+b  -> Cf fp32, Cb bf16
// EPI 2: v=acc+bias+gvec[b,col]; v=v*p0+p1; o=(resid+v)*p2+p3 -> Cf, Cb
template <int EPI>
__global__ __launch_bounds__(256) void k_gemmrow(
    const ushort_t* __restrict__ A, const ushort_t* __restrict__ Wt,
    const float* __restrict__ bias,
    ushort_t* __restrict__ Cb, float* __restrict__ Cf,
    const float* __restrict__ residf, const float* __restrict__ gvec,
    const float* __restrict__ p0, const float* __restrict__ p1,
    const float* __restrict__ p2, const float* __restrict__ p3) {
    const int K = 256;
    __shared__ __align__(16) ushort_t sA[2][2048];    // 32 x 64
    __shared__ __align__(16) ushort_t sB[2][16384];   // 256 x 64
    __shared__ float red[4][32][2];
    int tid = threadIdx.x;
    int lane = tid & 63, wv = tid >> 6;
    int rowBase = blockIdx.x * 32;
    int l16 = lane & 15, g = (lane >> 4) & 3;

    // staging sources (pre-swizzled global addresses)
    unsigned PA = (unsigned)tid * 16;
    unsigned LA = swz64(PA);
    const ushort_t* aSrc = A + (size_t)(rowBase + (LA >> 7)) * K + ((LA >> 1) & 63u);
    const ushort_t* bSrc[8];
    #pragma unroll
    for (int q = 0; q < 8; ++q) {
        unsigned P = q * 4096u + (unsigned)tid * 16;
        unsigned L = swz64(P);
        bSrc[q] = Wt + (size_t)(L >> 7) * K + ((L >> 1) & 63u);
    }
    unsigned wb = (unsigned)(tid >> 6) * 1024;

    unsigned oA[2][2], oB[4][2];
    #pragma unroll
    for (int mi = 0; mi < 2; ++mi)
        #pragma unroll
        for (int kk = 0; kk < 2; ++kk)
            oA[mi][kk] = swz64((unsigned)(((mi * 16 + l16) << 7) + (kk << 6) + (g << 4)));
    #pragma unroll
    for (int ni = 0; ni < 4; ++ni)
        #pragma unroll
        for (int kk = 0; kk < 2; ++kk)
            oB[ni][kk] = swz64((unsigned)(((wv * 64 + ni * 16 + l16) << 7) + (kk << 6) + (g << 4)));

    f32x4 acc[2][4] = {};
    const int nt = K >> 6;  // 4

    // prologue: stage tile 0 into buf 0
    GLL(aSrc, (char*)sA[0] + wb);
    #pragma unroll
    for (int q = 0; q < 8; ++q) GLL(bSrc[q], (char*)sB[0] + q * 4096 + wb);

    int cur = 0;
    for (int t = 0; t < nt; ++t) {
        if (t + 1 < nt) {
            int o = (t + 1) << 6;
            GLL(aSrc + o, (char*)sA[cur ^ 1] + wb);
            #pragma unroll
            for (int q = 0; q < 8; ++q) GLL(bSrc[q] + o, (char*)sB[cur ^ 1] + q * 4096 + wb);
            asm volatile("s_waitcnt vmcnt(9)" ::: "memory");
        } else {
            asm volatile("s_waitcnt vmcnt(0)" ::: "memory");
        }
        asm volatile("s_barrier" ::: "memory");
        const char* cA = (const char*)sA[cur];
        const char* cB = (const char*)sB[cur];
        #pragma unroll
        for (int kk = 0; kk < 2; ++kk) {
            bf16x8 a0 = *(const bf16x8*)(cA + oA[0][kk]);
            bf16x8 a1 = *(const bf16x8*)(cA + oA[1][kk]);
            bf16x8 b0 = *(const bf16x8*)(cB + oB[0][kk]);
            bf16x8 b1 = *(const bf16x8*)(cB + oB[1][kk]);
            bf16x8 b2 = *(const bf16x8*)(cB + oB[2][kk]);
            bf16x8 b3 = *(const bf16x8*)(cB + oB[3][kk]);
            acc[0][0] = __builtin_amdgcn_mfma_f32_16x16x32_bf16(a0, b0, acc[0][0], 0, 0, 0);
            acc[0][1] = __builtin_amdgcn_mfma_f32_16x16x32_bf16(a0, b1, acc[0][1], 0, 0, 0);
            acc[0][2] = __builtin_amdgcn_mfma_f32_16x16x32_bf16(a0, b2, acc[0][2], 0, 0, 0);
            acc[0][3] = __builtin_amdgcn_mfma_f32_16x16x32_bf16(a0, b3, acc[0][3], 0, 0, 0);
            acc[1][0] = __builtin_amdgcn_mfma_f32_16x16x32_bf16(a1, b0, acc[1][0], 0, 0, 0);
            acc[1][1] = __builtin_amdgcn_mfma_f32_16x16x32_bf16(a1, b1, acc[1][1], 0, 0, 0);
            acc[1][2] = __builtin_amdgcn_mfma_f32_16x16x32_bf16(a1, b2, acc[1][2], 0, 0, 0);
            acc[1][3] = __builtin_amdgcn_mfma_f32_16x16x32_bf16(a1, b3, acc[1][3], 0, 0, 0);
        }
        asm volatile("s_barrier" ::: "memory");
        cur ^= 1;
    }

    // add bias (cols wv*64 + ni*16 + l16)
    float bv[4];
    #pragma unroll
    for (int ni = 0; ni < 4; ++ni) bv[ni] = bias[wv * 64 + ni * 16 + l16];
    #pragma unroll
    for (int mi = 0; mi < 2; ++mi)
        #pragma unroll
        for (int ni = 0; ni < 4; ++ni)
            #pragma unroll
            for (int j = 0; j < 4; ++j)
                acc[mi][ni][j] += bv[ni];

    if constexpr (EPI == 4) {
        // per-row stats across wave's 64 cols, then cross-wave LDS reduce
        #pragma unroll
        for (int mi = 0; mi < 2; ++mi)
            #pragma unroll
            for (int j = 0; j < 4; ++j) {
                float s = 0.f, q = 0.f;
                #pragma unroll
                for (int ni = 0; ni < 4; ++ni) {
                    float vv = acc[mi][ni][j];
                    s += vv; q += vv * vv;
                }
                #pragma unroll
                for (int off = 1; off < 16; off <<= 1) {
                    s += __shfl_xor(s, off);
                    q += __shfl_xor(q, off);
                }
                if (l16 == 0) {
                    int r = mi * 16 + g * 4 + j;
                    red[wv][r][0] = s;
                    red[wv][r][1] = q;
                }
            }
        __syncthreads();
        #pragma unroll
        for (int mi = 0; mi < 2; ++mi)
            #pragma unroll
            for (int j = 0; j < 4; ++j) {
                int r = mi * 16 + g * 4 + j;
                float sum = red[0][r][0] + red[1][r][0] + red[2][r][0] + red[3][r][0];
                float sq  = red[0][r][1] + red[1][r][1] + red[2][r][1] + red[3][r][1];
                float mu = sum * (1.f / 256.f);
                float var = fmaxf(sq * (1.f / 256.f) - mu * mu, 0.f);
                float rs = rsqrtf(var + 1e-6f);
                int row = rowBase + r;
                #pragma unroll
                for (int ni = 0; ni < 4; ++ni) {
                    int col = wv * 64 + ni * 16 + l16;
                    size_t idx = (size_t)row * C_ + col;
                    float o = residf[idx] + (acc[mi][ni][j] - mu) * rs * p0[col] + p1[col];
                    Cf[idx] = o;
                    Cb[idx] = f2bf(o);
                }
            }
    } else {  // EPI == 2
        int bidx = rowBase >> 8;
        #pragma unroll
        for (int ni = 0; ni < 4; ++ni) {
            int col = wv * 64 + ni * 16 + l16;
            float gv = gvec[bidx * C_ + col];
            float s0v = p0[col], h0v = p1[col], s1v = p2[col], h1v = p3[col];
            #pragma unroll
            for (int mi = 0; mi < 2; ++mi)
                #pragma unroll
                for (int j = 0; j < 4; ++j) {
                    int row = rowBase + mi * 16 + g * 4 + j;
                    size_t idx = (size_t)row * C_ + col;
                    float v = acc[mi][ni][j] + gv;
                    v = v * s0v + h0v;
                    float o = (residf[idx] + v) * s1v + h1v;
                    Cf[idx] = o;
                    Cb[idx] = f2bf(o);
                }
        }
    }
}

// ------ FF GEMM: BM=128, BN(128|64), BK=64, 4 waves (2x2), wave 64x(BN/2) -----
// EPI 1: Cb = bf16(relu(acc+bias));  EPI 3: Cf = (residf + acc+bias)*p0 + p1
template <int EPI, int BN>
__global__ __launch_bounds__(256) void k_gemm128(
    const ushort_t* __restrict__ A, const ushort_t* __restrict__ Wt,
    const float* __restrict__ bias, int K, int Nn,
    ushort_t* __restrict__ Cb, float* __restrict__ Cf,
    const float* __restrict__ residf,
    const float* __restrict__ p0, const float* __restrict__ p1) {
    const int NI = BN / 32;           // 4 | 2  (wave col frags)
    const int QB = BN / 32;           // B chunks of 4KB: BN*128B/4096
    __shared__ __align__(16) ushort_t sA[2][8192];      // 128 x 64
    __shared__ __align__(16) ushort_t sB[2][BN * 64];
    int tid = threadIdx.x;
    int lane = tid & 63, wv = tid >> 6;
    int rowBase = blockIdx.y * 128, colBase = blockIdx.x * BN;
    int l16 = lane & 15, g = (lane >> 4) & 3;
    int wr = (wv >> 1) * 64, wc = (wv & 1) * (BN / 2);

    const ushort_t* aSrc[4];
    #pragma unroll
    for (int q = 0; q < 4; ++q) {
        unsigned P = q * 4096u + (unsigned)tid * 16;
        unsigned L = swz64(P);
        aSrc[q] = A + (size_t)(rowBase + (L >> 7)) * K + ((L >> 1) & 63u);
    }
    const ushort_t* bSrc[QB];
    #pragma unroll
    for (int q = 0; q < QB; ++q) {
        unsigned P = q * 4096u + (unsigned)tid * 16;
        unsigned L = swz64(P);
        bSrc[q] = Wt + (size_t)(colBase + (L >> 7)) * K + ((L >> 1) & 63u);
    }
    unsigned wb = (unsigned)(tid >> 6) * 1024;

    unsigned oA[4][2], oB[NI][2];
    #pragma unroll
    for (int mi = 0; mi < 4; ++mi)
        #pragma unroll
        for (int kk = 0; kk < 2; ++kk)
            oA[mi][kk] = swz64((unsigned)(((wr + mi * 16 + l16) << 7) + (kk << 6) + (g << 4)));
    #pragma unroll
    for (int ni = 0; ni < NI; ++ni)
        #pragma unroll
        for (int kk = 0; kk < 2; ++kk)
            oB[ni][kk] = swz64((unsigned)(((wc + ni * 16 + l16) << 7) + (kk << 6) + (g << 4)));

    f32x4 acc[4][NI] = {};
    int nt = K >> 6;

    #pragma unroll
    for (int q = 0; q < 4; ++q) GLL(aSrc[q], (char*)sA[0] + q * 4096 + wb);
    #pragma unroll
    for (int q = 0; q < QB; ++q) GLL(bSrc[q], (char*)sB[0] + q * 4096 + wb);

    int cur = 0;
    for (int t = 0; t < nt; ++t) {
        if (t + 1 < nt) {
            int o = (t + 1) << 6;
            #pragma unroll
            for (int q = 0; q < 4; ++q) GLL(aSrc[q] + o, (char*)sA[cur ^ 1] + q * 4096 + wb);
            #pragma unroll
            for (int q = 0; q < QB; ++q) GLL(bSrc[q] + o, (char*)sB[cur ^ 1] + q * 4096 + wb);
            if constexpr (BN == 128) asm volatile("s_waitcnt vmcnt(8)" ::: "memory");
            else                     asm volatile("s_waitcnt vmcnt(6)" ::: "memory");
        } else {
            asm volatile("s_waitcnt vmcnt(0)" ::: "memory");
        }
        asm volatile("s_barrier" ::: "memory");
        const char* cA = (const char*)sA[cur];
        const char* cB = (const char*)sB[cur];
        #pragma unroll
        for (int kk = 0; kk < 2; ++kk) {
            bf16x8 af[4], bf[NI];
            #pragma unroll
            for (int mi = 0; mi < 4; ++mi) af[mi] = *(const bf16x8*)(cA + oA[mi][kk]);
            #pragma unroll
            for (int ni = 0; ni < NI; ++ni) bf[ni] = *(const bf16x8*)(cB + oB[ni][kk]);
            #pragma unroll
            for (int mi = 0; mi < 4; ++mi)
                #pragma unroll
                for (int ni = 0; ni < NI; ++ni)
                    acc[mi][ni] = __builtin_amdgcn_mfma_f32_16x16x32_bf16(af[mi], bf[ni], acc[mi][ni], 0, 0, 0);
        }
        asm volatile("s_barrier" ::: "memory");
        cur ^= 1;
    }

    #pragma unroll
    for (int ni = 0; ni < NI; ++ni) {
        int col = colBase + wc + ni * 16 + l16;
        float bvv = bias[col];
        float s0v = 0.f, h0v = 0.f;
        if constexpr (EPI == 3) { s0v = p0[col]; h0v = p1[col]; }
        #pragma unroll
        for (int mi = 0; mi < 4; ++mi)
            #pragma unroll
            for (int j = 0; j < 4; ++j) {
                int row = rowBase + wr + mi * 16 + g * 4 + j;
                size_t idx = (size_t)row * Nn + col;
                float v = acc[mi][ni][j] + bvv;
                if constexpr (EPI == 1) {
                    Cb[idx] = f2bf(fmaxf(v, 0.f));
                } else {
                    Cf[idx] = (residf[idx] + v) * s0v + h0v;
                }
            }
    }
}

// ------------- gctx = mean over N (coalesced), then gvec = gctx@w1+b1 ---------
__global__ __launch_bounds__(256) void k_gctxvec(
        const float* __restrict__ x1f, const float* __restrict__ w1,
        const float* __restrict__ b1, float* __restrict__ gvec) {
    int b = blockIdx.x, tid = threadIdx.x;
    int h = tid >> 6, lane = tid & 63;
    __shared__ float part[4][C_];
    __shared__ float sg[C_];
    const float* base = x1f + (size_t)b * N_ * C_ + h * 64 * C_ + lane * 4;
    float4 a = {0.f, 0.f, 0.f, 0.f};
    for (int n = 0; n < 64; ++n) {
        float4 v = *(const float4*)(base + n * C_);
        a.x += v.x; a.y += v.y; a.z += v.z; a.w += v.w;
    }
    *(float4*)(&part[h][lane * 4]) = a;
    __syncthreads();
    int j = tid;
    sg[j] = (part[0][j] + part[1][j] + part[2][j] + part[3][j]) * (1.f / 256.f);
    __syncthreads();
    float acc = b1[j];
    #pragma unroll 8
    for (int c = 0; c < C_; ++c) acc = fmaf(sg[c], w1[c * C_ + j], acc);
    gvec[b * C_ + j] = acc;
}

extern "C" void kernel_launch(void* const* d_in, const int* in_sizes, int n_in,
                              void* d_out, int out_size, void* d_ws, size_t ws_size,
                              hipStream_t stream) {
    const float* x      = (const float*)d_in[0];
    const float* coords = (const float*)d_in[1];
    const float* dwk    = (const float*)d_in[2];
    const float* dwb    = (const float*)d_in[3];
    const float* pw_w   = (const float*)d_in[4];
    const float* pw_b   = (const float*)d_in[5];
    const float* ln_g   = (const float*)d_in[6];
    const float* ln_b   = (const float*)d_in[7];
    const float* gi_w1  = (const float*)d_in[8];
    const float* gi_b1  = (const float*)d_in[9];
    const float* gi_w2  = (const float*)d_in[10];
    const float* gi_b2  = (const float*)d_in[11];
    const float* bn0g = (const float*)d_in[12], *bn0b = (const float*)d_in[13];
    const float* bn0m = (const float*)d_in[14], *bn0v = (const float*)d_in[15];
    const float* bn1g = (const float*)d_in[16], *bn1b = (const float*)d_in[17];
    const float* bn1m = (const float*)d_in[18], *bn1v = (const float*)d_in[19];
    const float* bn2g = (const float*)d_in[20], *bn2b = (const float*)d_in[21];
    const float* bn2m = (const float*)d_in[22], *bn2v = (const float*)d_in[23];
    const float* w_ff1 = (const float*)d_in[24];
    const float* b_ff1 = (const float*)d_in[25];
    const float* w_ff2 = (const float*)d_in[26];
    const float* b_ff2 = (const float*)d_in[27];

    char* ws = (char*)d_ws;
    int*      ncnt = (int*)(ws + 0);
    float*    gvec = (float*)(ws + 65536);
    float*    bnsh = (float*)(ws + 98304);
    ushort_t* WtPW = (ushort_t*)(ws + 131072);
    ushort_t* WtGI = (ushort_t*)(ws + 262144);
    ushort_t* WtF1 = (ushort_t*)(ws + 393216);
    ushort_t* WtF2 = (ushort_t*)(ws + 917504);
    ushort_t* nbr  = (ushort_t*)(ws + 1441792);   // 4 MB
    ushort_t* bufT = (ushort_t*)(ws + 5636096);   // 4 MB: t0, then x1_bf (in-place)
    ushort_t* bufH = (ushort_t*)(ws + 9830400);   // 4 MB: x2_bf
    float*    x1f  = (float*)(ws + 14024704);     // 8 MB
    float*    x2f  = (float*)(ws + 22413312);     // 8 MB
    ushort_t* u_b  = (ushort_t*)(ws + 30801920);  // 16 MB
    float*    outx = (float*)d_out;

    const int M = B_ * N_;  // 8192

    k_geo<<<B_ + 1, N_, 0, stream>>>(coords, nbr, ncnt,
                                     bn0g, bn0b, bn0m, bn0v,
                                     bn1g, bn1b, bn1m, bn1v,
                                     bn2g, bn2b, bn2m, bn2v,
                                     bnsh, outx + (size_t)M * C_);
    k_wprep<<<640, 256, 0, stream>>>(pw_w, gi_w2, w_ff1, w_ff2, WtPW, WtGI, WtF1, WtF2);
    k_cpe2<<<M / 4, 256, 0, stream>>>(x, nbr, ncnt, dwk, dwb, bufT);

    // GEMM1 + LN fused: x1 = x + LN(t0@pw_w + pw_b)  -> x1f fp32, bufT bf16 (in place)
    k_gemmrow<4><<<M / 32, 256, 0, stream>>>(
        bufT, WtPW, pw_b, bufT, x1f,
        x, nullptr, ln_g, ln_b, nullptr, nullptr);

    // gvec = (mean_n x1) @ gi_w1 + gi_b1
    k_gctxvec<<<B_, 256, 0, stream>>>(x1f, gi_w1, gi_b1, gvec);

    // x2 = bn1(x1 + bn0(x1@gi_w2 + gi_b2 + gvec)) -> x2f fp32, bufH bf16
    k_gemmrow<2><<<M / 32, 256, 0, stream>>>(
        bufT, WtGI, gi_b2, bufH, x2f,
        x1f, gvec, bnsh, bnsh + 256, bnsh + 512, bnsh + 768);

    // u = relu(x2 @ w_ff1 + b_ff1) -> u_b bf16
    k_gemm128<1, 128><<<dim3(DFF_ / 128, M / 128), 256, 0, stream>>>(
        bufH, WtF1, b_ff1, C_, DFF_, u_b, nullptr, nullptr, nullptr, nullptr);

    // out = bn2(x2 + u @ w_ff2 + b_ff2)
    k_gemm128<3, 64><<<dim3(C_ / 64, M / 128), 256, 0, stream>>>(
        u_b, WtF2, b_ff2, DFF_, C_, nullptr, outx,
        x2f, bnsh + 1024, bnsh + 1280);
}